// Round 2
// baseline (2891.422 us; speedup 1.0000x reference)
//
#include <hip/hip_runtime.h>

#define B_ 2048
#define T_ 128
#define S_ 256
#define V_ 29
#define E_ 32
#define H_ 64

// Swizzled float4 index for enc quad (s, h4). Conflict-free for BOTH:
//  - row pattern (fixed i, lanes = consecutive s):  bank-quad = (i+s+(s>>4))&7 cycles over 8 lanes
//  - col pattern (fixed j, lanes = (hq,sq)):        bank-quad = (hq+j+sq)&7, 8 lanes per quad
__device__ __forceinline__ int enc_idx(int s, int h4) {
    return s * 16 + ((h4 + s + (s >> 4)) & 15);
}

// ---------------------------------------------------------------------------
// Precompute (1 block):
//   gate_emb[v][g] = b_ih[g] + b_hh[g] + sum_e emb_table[v,e] * W_ih[g,e]
//   Wcat[g][0:64]  = W_ih[g][32:96]   (context part)
//   Wcat[g][64:128]= W_hh[g][0:64]
// ---------------------------------------------------------------------------
__global__ __launch_bounds__(256) void precompute_kernel(
    const float* __restrict__ emb_table, const float* __restrict__ W_ih,
    const float* __restrict__ W_hh, const float* __restrict__ b_ih,
    const float* __restrict__ b_hh, float* __restrict__ ws)
{
    const int g = threadIdx.x;
    float wemb[32];
#pragma unroll
    for (int e = 0; e < 32; ++e) wemb[e] = W_ih[g * 96 + e];
    const float bb = b_ih[g] + b_hh[g];
    for (int v = 0; v < V_; ++v) {
        float acc = bb;
#pragma unroll
        for (int e = 0; e < 32; ++e) acc = fmaf(emb_table[v * 32 + e], wemb[e], acc);
        ws[v * 256 + g] = acc;
    }
    float* wcat = ws + V_ * 256;
#pragma unroll
    for (int k = 0; k < 64; ++k) wcat[g * 128 + k] = W_ih[g * 96 + 32 + k];
#pragma unroll
    for (int k = 0; k < 64; ++k) wcat[g * 128 + 64 + k] = W_hh[g * 64 + k];
}

// ---------------------------------------------------------------------------
// Main decoder: 1 block = 1 batch row, 256 threads, T=128 steps, 5 barriers/step.
// enc row in LDS (context pass) AND per-thread registers (scores pass).
// Gate weights in registers (thread g owns gate g); fc_W 16 floats/thread.
// ---------------------------------------------------------------------------
__global__ __launch_bounds__(256, 2) void decoder_kernel(
    const int* __restrict__ y, const float* __restrict__ h0,
    const float* __restrict__ c0, const float* __restrict__ enc,
    const float* __restrict__ fc_W, const float* __restrict__ fc_b,
    const float* __restrict__ ws, float* __restrict__ out)
{
    __shared__ float4 encS[S_ * 16];                  // 64 KB, swizzled
    __shared__ float attn[256];                       // e values, reused as gates buf
    __shared__ __align__(16) float vec128[128];       // [context(64) | h(64)]
    __shared__ float cvec[64];
    __shared__ int yrow[T_];
    __shared__ float red[128];                        // logits reduction
    __shared__ float redsum[4];

    const int tid = threadIdx.x;
    const int b = blockIdx.x;
    const int wid = tid >> 6;
    const int lane = tid & 63;

    // --- per-thread weight registers ---
    const float* wcat = ws + V_ * 256;
    float4 w4[32];
#pragma unroll
    for (int q = 0; q < 32; ++q) w4[q] = ((const float4*)(wcat + tid * 128))[q];

    const int v = tid & 31;
    const int jj = tid >> 5;  // 0..7; k-range 16*jj of combined[128] = [h | ctx]
    float4 fcw4[4];
    float fcb = 0.f;
    if (v < V_) {
#pragma unroll
        for (int q = 0; q < 4; ++q)
            fcw4[q] = ((const float4*)(fc_W + v * 128 + jj * 16))[q];
        fcb = fc_b[v];
    } else {
#pragma unroll
        for (int q = 0; q < 4; ++q) fcw4[q] = make_float4(0.f, 0.f, 0.f, 0.f);
    }

    // --- stage enc row into LDS (swizzled), init h/c/y ---
    {
        const float4* encg = (const float4*)(enc + (size_t)b * S_ * H_);
#pragma unroll
        for (int i = 0; i < 16; ++i) {
            int f4 = i * 256 + tid;
            int s = f4 >> 4, h4 = f4 & 15;
            encS[enc_idx(s, h4)] = encg[f4];
        }
    }
    if (tid < 64) {
        vec128[64 + tid] = h0[b * 64 + tid];
        cvec[tid] = c0[b * 64 + tid];
    }
    if (tid < T_) yrow[tid] = y[b * T_ + tid];
    __syncthreads();

    // --- per-thread register copy of enc row s = tid (for scores pass) ---
    float4 er[16];
#pragma unroll
    for (int i = 0; i < 16; ++i) er[i] = encS[enc_idx(tid, i)];

    // context-pass lane mapping: wave covers ALL s for its 16 h's
    const int hq = lane >> 4;           // 0..3
    const int sq = lane & 15;           // s-chunk of 16
    const int hqg = wid * 4 + hq;       // global h-quad 0..15

    for (int t = 0; t < T_; ++t) {
        const int yt = yrow[t];
        const float ge = ws[yt * 256 + tid];  // gate_emb, L2-hot, used in P3

        // ---- P1: scores for s=tid from registers; exp; wave-sum
        float sc = 0.f;
#pragma unroll
        for (int i = 0; i < 16; ++i) {
            float4 h4v = *(const float4*)&vec128[64 + 4 * i];
            sc += er[i].x * h4v.x + er[i].y * h4v.y + er[i].z * h4v.z + er[i].w * h4v.w;
        }
        float e = __expf(fminf(sc, 60.f));   // no max-pass; clamp guards overflow
        float ssum = e;
#pragma unroll
        for (int off = 32; off >= 1; off >>= 1) ssum += __shfl_xor(ssum, off);
        attn[tid] = e;
        if (lane == 0) redsum[wid] = ssum;
        __syncthreads();  // BA: attn (e), redsum ready

        // ---- P2: context, normalized by 1/sum. Lane (hq,sq) covers s-chunk sq
        //      for h-quad hqg; shuffle-reduce over sq (offsets 1,2,4,8).
        {
            const float inv = 1.f / (redsum[0] + redsum[1] + redsum[2] + redsum[3]);
            float4 acc = make_float4(0.f, 0.f, 0.f, 0.f);
#pragma unroll
            for (int q = 0; q < 4; ++q) {
                float4 a4 = *(const float4*)&attn[sq * 16 + 4 * q];
#pragma unroll
                for (int j2 = 0; j2 < 4; ++j2) {
                    int s = sq * 16 + 4 * q + j2;
                    float4 e4 = encS[enc_idx(s, hqg)];
                    float aw = (&a4.x)[j2];
                    acc.x = fmaf(aw, e4.x, acc.x);
                    acc.y = fmaf(aw, e4.y, acc.y);
                    acc.z = fmaf(aw, e4.z, acc.z);
                    acc.w = fmaf(aw, e4.w, acc.w);
                }
            }
#pragma unroll
            for (int off = 1; off <= 8; off <<= 1) {
                acc.x += __shfl_xor(acc.x, off);
                acc.y += __shfl_xor(acc.y, off);
                acc.z += __shfl_xor(acc.z, off);
                acc.w += __shfl_xor(acc.w, off);
            }
            if (sq == 0) {
                float4 r = make_float4(acc.x * inv, acc.y * inv, acc.z * inv, acc.w * inv);
                *(float4*)&vec128[4 * hqg] = r;
            }
        }
        __syncthreads();  // BB: vec128[0:64] (context) ready; h unchanged

        // ---- P3: gates, thread g = tid, weights in registers
        float gacc = ge;
#pragma unroll
        for (int q = 0; q < 32; ++q) {
            float4 x4 = *(const float4*)&vec128[4 * q];
            gacc += w4[q].x * x4.x + w4[q].y * x4.y + w4[q].z * x4.z + w4[q].w * x4.w;
        }
        attn[tid] = gacc;  // reuse attn[] as gates buffer (last read was pre-BB)
        __syncthreads();  // BC: gates ready

        // ---- P4: LSTM pointwise (wave 0 lanes)
        if (tid < 64) {
            float gi = attn[tid], gf = attn[64 + tid], gg = attn[128 + tid], go = attn[192 + tid];
            float si = 1.f / (1.f + __expf(-gi));
            float sf = 1.f / (1.f + __expf(-gf));
            float so = 1.f / (1.f + __expf(-go));
            float tg = 1.f - 2.f / (__expf(2.f * gg) + 1.f);
            float cn = sf * cvec[tid] + si * tg;
            cvec[tid] = cn;
            float hn = so * (1.f - 2.f / (__expf(2.f * cn) + 1.f));
            vec128[64 + tid] = hn;
        }
        __syncthreads();  // BD: h_new ready

        // ---- P5: logits; combined[k] = vec128[k ^ 64]
        {
            const int base = (jj < 4) ? (64 + 16 * jj) : (16 * jj - 64);
            float acc = 0.f;
#pragma unroll
            for (int q = 0; q < 4; ++q) {
                float4 c4 = *(const float4*)&vec128[base + 4 * q];
                acc += fcw4[q].x * c4.x + fcw4[q].y * c4.y + fcw4[q].z * c4.z + fcw4[q].w * c4.w;
            }
            acc += __shfl_xor(acc, 32);               // fold jj pairs
            if ((tid & 32) == 0) red[wid * 32 + v] = acc;
        }
        __syncthreads();  // BE: red ready
        if (tid < V_) {
            float r = red[tid] + red[32 + tid] + red[64 + tid] + red[96 + tid] + fcb;
            out[((size_t)b * T_ + t) * V_ + tid] = r;
        }
        // next iter's first shared write (attn[tid]=e) happens after BE for all
        // threads; all prior readers of attn finished before BD. Safe.
    }
}

extern "C" void kernel_launch(void* const* d_in, const int* in_sizes, int n_in,
                              void* d_out, int out_size, void* d_ws, size_t ws_size,
                              hipStream_t stream)
{
    const int*   y    = (const int*)  d_in[0];
    const float* h0   = (const float*)d_in[1];
    const float* c0   = (const float*)d_in[2];
    const float* enc  = (const float*)d_in[3];
    const float* emb  = (const float*)d_in[4];
    const float* W_ih = (const float*)d_in[5];
    const float* W_hh = (const float*)d_in[6];
    const float* b_ih = (const float*)d_in[7];
    const float* b_hh = (const float*)d_in[8];
    const float* fc_W = (const float*)d_in[9];
    const float* fc_b = (const float*)d_in[10];
    float* ws  = (float*)d_ws;   // needs (29*256 + 256*128)*4 = 157 KB
    float* out = (float*)d_out;

    precompute_kernel<<<1, 256, 0, stream>>>(emb, W_ih, W_hh, b_ih, b_hh, ws);
    decoder_kernel<<<B_, 256, 0, stream>>>(y, h0, c0, enc, fc_W, fc_b, ws, out);
}

// Round 3
// 1745.191 us; speedup vs baseline: 1.6568x; 1.6568x over previous
//
#include <hip/hip_runtime.h>

#define B_ 2048
#define T_ 128
#define S_ 256
#define V_ 29

// Swizzled float4 index for enc quad (s, h4):
//  - row pattern (fixed h4-loop, lanes = consecutive s): conflict-free
//  - col pattern (fixed s-offset, lanes = (hq,sq)):      conflict-free
__device__ __forceinline__ int enc_idx(int s, int h4) {
    return s * 16 + ((h4 + s + (s >> 4)) & 15);
}

// ---------------------------------------------------------------------------
// Precompute (1 block, 256 threads). Thread g owns gate row g = q*64 + j
// (q = gate block i/f/g/o, j = hidden index). The decoder thread that will
// consume row g is tidg = (j>>4)*64 + (j&15)*4 + q  (quad-of-lanes layout).
//   ws[0 .. 29*256)          gate_embP[v][tidg] = b_ih[g]+b_hh[g]+emb[v]·W_ih[g,0:32]
//   ws[29*256 .. +256*128)   wcatP[tidg][0:64]=W_ih[g][32:96], [64:128]=W_hh[g]
// ---------------------------------------------------------------------------
__global__ __launch_bounds__(256) void precompute_kernel(
    const float* __restrict__ emb_table, const float* __restrict__ W_ih,
    const float* __restrict__ W_hh, const float* __restrict__ b_ih,
    const float* __restrict__ b_hh, float* __restrict__ ws)
{
    const int g = threadIdx.x;
    const int q = g >> 6, j = g & 63;
    const int tidg = (j >> 4) * 64 + (j & 15) * 4 + q;

    float wemb[32];
#pragma unroll
    for (int e = 0; e < 32; ++e) wemb[e] = W_ih[g * 96 + e];
    const float bb = b_ih[g] + b_hh[g];
    for (int v = 0; v < V_; ++v) {
        float acc = bb;
#pragma unroll
        for (int e = 0; e < 32; ++e) acc = fmaf(emb_table[v * 32 + e], wemb[e], acc);
        ws[v * 256 + tidg] = acc;
    }
    float* wcatP = ws + V_ * 256;
#pragma unroll
    for (int k = 0; k < 64; ++k) wcatP[tidg * 128 + k] = W_ih[g * 96 + 32 + k];
#pragma unroll
    for (int k = 0; k < 64; ++k) wcatP[tidg * 128 + 64 + k] = W_hh[g * 64 + k];
}

// ---------------------------------------------------------------------------
// Main decoder: 1 block = 1 batch row, 256 threads, T=128 steps, 4 barriers/step.
// ---------------------------------------------------------------------------
__global__ __launch_bounds__(256, 2) void decoder_kernel(
    const int* __restrict__ y, const float* __restrict__ h0,
    const float* __restrict__ c0, const float* __restrict__ enc,
    const float* __restrict__ fc_W, const float* __restrict__ fc_b,
    const float* __restrict__ ws, float* __restrict__ out)
{
    __shared__ float4 encS[S_ * 16];                  // 64 KB, swizzled
    __shared__ float4 attnP[16 * 17];                 // padded e-values (4.25 KB)
    __shared__ __align__(16) float ctxv[64];          // context
    __shared__ __align__(16) float hbuf[2][64];       // double-buffered h
    __shared__ float red[128];                        // logits reduction
    __shared__ float redsum[4];
    __shared__ int yrow[T_];

    const int tid = threadIdx.x;
    const int b = blockIdx.x;
    const int wid = tid >> 6;
    const int lane = tid & 63;

    // --- gate row registers (permuted ownership: quad lane qg, hidden jg) ---
    const int qg = lane & 3;
    const int jg = wid * 16 + (lane >> 2);
    const float* wcatP = ws + V_ * 256;
    float4 w4[32];
#pragma unroll
    for (int k = 0; k < 32; ++k) w4[k] = ((const float4*)(wcatP + tid * 128))[k];

    // --- fc registers: thread (v = tid&31, jj = tid>>5) covers 16 k's ---
    const int v = tid & 31;
    const int jj = tid >> 5;
    float4 fcw4[4];
    float fcb = 0.f;
    if (v < V_) {
#pragma unroll
        for (int k = 0; k < 4; ++k)
            fcw4[k] = ((const float4*)(fc_W + v * 128 + jj * 16))[k];
        fcb = fc_b[v];
    } else {
#pragma unroll
        for (int k = 0; k < 4; ++k) fcw4[k] = make_float4(0.f, 0.f, 0.f, 0.f);
    }

    // --- stage enc row into LDS (swizzled), init h/c/y ---
    {
        const float4* encg = (const float4*)(enc + (size_t)b * S_ * 64);
#pragma unroll
        for (int i = 0; i < 16; ++i) {
            int f4 = i * 256 + tid;
            int s = f4 >> 4, h4 = f4 & 15;
            encS[enc_idx(s, h4)] = encg[f4];
        }
    }
    if (tid < 64) hbuf[0][tid] = h0[b * 64 + tid];
    float creg = c0[b * 64 + jg];                     // c state lives in a register
    if (tid < T_) yrow[tid] = y[b * T_ + tid];
    __syncthreads();

    // context-pass lane mapping
    const int hq = lane >> 4;           // 0..3
    const int sq = lane & 15;           // s-chunk of 16
    const int hqg = wid * 4 + hq;       // global h-quad 0..15
    const int tsw = tid + (tid >> 4);   // hoisted swizzle term for P1

    float* attnPf = (float*)attnP;

    for (int t = 0; t < T_; ++t) {
        const int cur = t & 1, nxt = cur ^ 1;
        const int yt = yrow[t];
        const float ge = ws[yt * 256 + tid];          // gate_embP, L2-hot

        // ---- P1: score for s = tid; exp; wave-sum; padded attn store
        float sc = 0.f;
#pragma unroll
        for (int i = 0; i < 16; ++i) {
            float4 e4 = encS[tid * 16 + ((i + tsw) & 15)];
            float4 h4v = *(const float4*)&hbuf[cur][4 * i];
            sc += e4.x * h4v.x + e4.y * h4v.y + e4.z * h4v.z + e4.w * h4v.w;
        }
        float e = __expf(fminf(sc, 60.f));
        float ssum = e;
#pragma unroll
        for (int off = 32; off >= 1; off >>= 1) ssum += __shfl_xor(ssum, off);
        attnPf[(tid >> 4) * 68 + (tid & 15)] = e;
        if (lane == 0) redsum[wid] = ssum;
        __syncthreads();  // BA

        // ---- P2: full context per wave; lane (hq,sq) covers s-chunk sq for h-quad hqg
        {
            const float inv = __builtin_amdgcn_rcpf(redsum[0] + redsum[1] + redsum[2] + redsum[3]);
            float4 acc = make_float4(0.f, 0.f, 0.f, 0.f);
#pragma unroll
            for (int k = 0; k < 4; ++k) {
                float4 a4 = attnP[sq * 17 + k];
#pragma unroll
                for (int j2 = 0; j2 < 4; ++j2) {
                    int s = sq * 16 + 4 * k + j2;
                    float4 e4 = encS[s * 16 + ((hqg + s + sq) & 15)];
                    float aw = (&a4.x)[j2];
                    acc.x = fmaf(aw, e4.x, acc.x);
                    acc.y = fmaf(aw, e4.y, acc.y);
                    acc.z = fmaf(aw, e4.z, acc.z);
                    acc.w = fmaf(aw, e4.w, acc.w);
                }
            }
#pragma unroll
            for (int off = 1; off <= 8; off <<= 1) {
                acc.x += __shfl_xor(acc.x, off);
                acc.y += __shfl_xor(acc.y, off);
                acc.z += __shfl_xor(acc.z, off);
                acc.w += __shfl_xor(acc.w, off);
            }
            if (sq == 0) {
                float4 r = make_float4(acc.x * inv, acc.y * inv, acc.z * inv, acc.w * inv);
                *(float4*)&ctxv[4 * hqg] = r;
            }
        }
        __syncthreads();  // BB

        // ---- P3: gate dot (row qg*64+jg) + quad-shuffle LSTM, no barrier inside
        {
            float gacc = ge;
#pragma unroll
            for (int k = 0; k < 16; ++k) {
                float4 x4 = *(const float4*)&ctxv[4 * k];
                gacc += w4[k].x * x4.x + w4[k].y * x4.y + w4[k].z * x4.z + w4[k].w * x4.w;
            }
#pragma unroll
            for (int k = 0; k < 16; ++k) {
                float4 x4 = *(const float4*)&hbuf[cur][4 * k];
                gacc += w4[16 + k].x * x4.x + w4[16 + k].y * x4.y + w4[16 + k].z * x4.z + w4[16 + k].w * x4.w;
            }
            const float v1 = __shfl_xor(gacc, 1);
            const float v2 = __shfl_xor(gacc, 2);
            const float v3 = __shfl_xor(gacc, 3);
            // value of gate block p is [gacc,v1,v2,v3][p ^ qg]
            const bool b1 = qg & 1, b2 = qg & 2;
            const float gi = b2 ? (b1 ? v3 : v2) : (b1 ? v1 : gacc);
            const float gf = b2 ? (b1 ? v2 : v3) : (b1 ? gacc : v1);
            const float gg = b2 ? (b1 ? v1 : gacc) : (b1 ? v3 : v2);
            const float go = b2 ? (b1 ? gacc : v1) : (b1 ? v2 : v3);
            const float si = __builtin_amdgcn_rcpf(1.f + __expf(-gi));
            const float sf = __builtin_amdgcn_rcpf(1.f + __expf(-gf));
            const float so = __builtin_amdgcn_rcpf(1.f + __expf(-go));
            const float tg = 1.f - 2.f * __builtin_amdgcn_rcpf(__expf(2.f * gg) + 1.f);
            creg = sf * creg + si * tg;
            const float hn = so * (1.f - 2.f * __builtin_amdgcn_rcpf(__expf(2.f * creg) + 1.f));
            if (qg == 0) hbuf[nxt][jg] = hn;
        }
        __syncthreads();  // BD

        // ---- P5: logits; combined = [h_new | ctx]
        {
            const float* basep = (jj < 4) ? &hbuf[nxt][16 * jj] : &ctxv[16 * jj - 64];
            float acc = 0.f;
#pragma unroll
            for (int k = 0; k < 4; ++k) {
                float4 c4 = *(const float4*)(basep + 4 * k);
                acc += fcw4[k].x * c4.x + fcw4[k].y * c4.y + fcw4[k].z * c4.z + fcw4[k].w * c4.w;
            }
            acc += __shfl_xor(acc, 32);               // fold jj pairs
            if ((tid & 32) == 0) red[wid * 32 + v] = acc;
        }
        __syncthreads();  // BE
        if (tid < V_) {
            float r = red[tid] + red[32 + tid] + red[64 + tid] + red[96 + tid] + fcb;
            out[((size_t)b * T_ + t) * V_ + tid] = r;
        }
    }
}

extern "C" void kernel_launch(void* const* d_in, const int* in_sizes, int n_in,
                              void* d_out, int out_size, void* d_ws, size_t ws_size,
                              hipStream_t stream)
{
    const int*   y    = (const int*)  d_in[0];
    const float* h0   = (const float*)d_in[1];
    const float* c0   = (const float*)d_in[2];
    const float* enc  = (const float*)d_in[3];
    const float* emb  = (const float*)d_in[4];
    const float* W_ih = (const float*)d_in[5];
    const float* W_hh = (const float*)d_in[6];
    const float* b_ih = (const float*)d_in[7];
    const float* b_hh = (const float*)d_in[8];
    const float* fc_W = (const float*)d_in[9];
    const float* fc_b = (const float*)d_in[10];
    float* ws  = (float*)d_ws;   // needs (29*256 + 256*128)*4 = 157 KB
    float* out = (float*)d_out;

    precompute_kernel<<<1, 256, 0, stream>>>(emb, W_ih, W_hh, b_ih, b_hh, ws);
    decoder_kernel<<<B_, 256, 0, stream>>>(y, h0, c0, enc, fc_W, fc_b, ws, out);
}